// Round 11
// baseline (260.004 us; speedup 1.0000x reference)
//
#include <hip/hip_runtime.h>

constexpr int D_IN = 20;   // input feature dim
constexpr int HP   = 16;   // projection dim
constexpr int K    = 6;    // neighbors
constexpr int SAMP = 512;  // threshold sample size
constexpr int CAP  = 768;  // per-row candidate buffer capacity
constexpr float MARGIN = 0.02f;  // covers bf16-vs-fp32 dot error (<=~0.008)

typedef __attribute__((ext_vector_type(8))) short bf16x8;
typedef __attribute__((ext_vector_type(4))) float f32x4;

// Sequential fmaf dot — MUST be bit-identical across thresh/final.
__device__ __forceinline__ float dot16_seq(const float4* q, const float4* c) {
  float s = 0.f;
#pragma unroll
  for (int m = 0; m < 4; ++m) {
    s = fmaf(q[m].x, c[m].x, s);
    s = fmaf(q[m].y, c[m].y, s);
    s = fmaf(q[m].z, c[m].z, s);
    s = fmaf(q[m].w, c[m].w, s);
  }
  return s;
}

// round-to-nearest-even f32 -> bf16 bits
__device__ __forceinline__ short f2bf(float f) {
  unsigned u = __float_as_uint(f);
  unsigned r = (u + 0x7fffu + ((u >> 16) & 1u)) >> 16;
  return (short)r;
}

// ---- projection + row-normalize + bf16 copy + XW0 + counter zeroing ----
__global__ void k_proj(const float* __restrict__ x, const float* __restrict__ Wp,
                       const float* __restrict__ bp, const float* __restrict__ gw0,
                       float* __restrict__ hn, short* __restrict__ hnb,
                       float* __restrict__ XW0,
                       float* __restrict__ insum, int* __restrict__ indeg, int N) {
  int i = blockIdx.x * blockDim.x + threadIdx.x;
  if (i >= N) return;
  insum[i] = 0.f; indeg[i] = 0;
  float xr[D_IN];
#pragma unroll
  for (int d = 0; d < D_IN; ++d) xr[d] = x[i*D_IN + d];
  float hv[HP];
  float nrm2 = 0.f;
#pragma unroll
  for (int h = 0; h < HP; ++h) {
    float a = bp[h];
#pragma unroll
    for (int d = 0; d < D_IN; ++d) a += xr[d] * Wp[d*HP + h];
    hv[h] = a;
    nrm2 += a * a;
  }
  float inv = 1.f / fmaxf(sqrtf(nrm2), 1e-12f);
#pragma unroll
  for (int h = 0; h < HP; ++h) {
    float v = hv[h] * inv;
    hn[i*HP + h] = v;
    hnb[(size_t)i*32 + h] = f2bf(v);
  }
#pragma unroll
  for (int h = 0; h < HP; ++h) hnb[(size_t)i*32 + 16 + h] = 0;
  // fused XW0 = x @ gw0 (bias added in k_gpost)
#pragma unroll
  for (int oc = 0; oc < 32; ++oc) {
    float a = 0.f;
#pragma unroll
    for (int d = 0; d < D_IN; ++d) a += xr[d] * gw0[d*32 + oc];
    XW0[(size_t)i*32 + oc] = a;
  }
}

// ---------------- per-lane top-6 in NAMED registers ----
struct Top6 { float v0,v1,v2,v3,v4,v5; int i0,i1,i2,i3,i4,i5; };

__device__ __forceinline__ void t6_init(Top6& t) {
  t.v0=t.v1=t.v2=t.v3=t.v4=t.v5=-1e30f;
  t.i0=t.i1=t.i2=t.i3=t.i4=t.i5=-1;
}

#define T6_SWAP(a,b,ia,ib) { float tv=a; a=b; b=tv; int ti=ia; ia=ib; ib=ti; }

__device__ __forceinline__ void t6_insert(Top6& t, float s, int c) {
  if (s > t.v5) {
    t.v5 = s; t.i5 = c;
    if (t.v5 > t.v4) { T6_SWAP(t.v4, t.v5, t.i4, t.i5); }
    if (t.v4 > t.v3) { T6_SWAP(t.v3, t.v4, t.i3, t.i4); }
    if (t.v3 > t.v2) { T6_SWAP(t.v2, t.v3, t.i2, t.i3); }
    if (t.v2 > t.v1) { T6_SWAP(t.v1, t.v2, t.i1, t.i2); }
    if (t.v1 > t.v0) { T6_SWAP(t.v0, t.v1, t.i0, t.i1); }
  }
}

__device__ __forceinline__ void t6_best(const Top6& t, float& cv, int& ci) {
  cv = t.v0; ci = t.i0;
  if (t.v1 > cv || (t.v1 == cv && (unsigned)t.i1 < (unsigned)ci)) { cv = t.v1; ci = t.i1; }
  if (t.v2 > cv || (t.v2 == cv && (unsigned)t.i2 < (unsigned)ci)) { cv = t.v2; ci = t.i2; }
  if (t.v3 > cv || (t.v3 == cv && (unsigned)t.i3 < (unsigned)ci)) { cv = t.v3; ci = t.i3; }
  if (t.v4 > cv || (t.v4 == cv && (unsigned)t.i4 < (unsigned)ci)) { cv = t.v4; ci = t.i4; }
  if (t.v5 > cv || (t.v5 == cv && (unsigned)t.i5 < (unsigned)ci)) { cv = t.v5; ci = t.i5; }
}

__device__ __forceinline__ void t6_consume(Top6& t, int mi) {
  if (t.i0 == mi) t.v0 = -1e30f;
  if (t.i1 == mi) t.v1 = -1e30f;
  if (t.i2 == mi) t.v2 = -1e30f;
  if (t.i3 == mi) t.v3 = -1e30f;
  if (t.i4 == mi) t.v4 = -1e30f;
  if (t.i5 == mi) t.v5 = -1e30f;
}

// ---------------- threshold pass: exact 6th-largest over SAMP-sample, wave per row
__global__ __launch_bounds__(256) void k_thresh(const float* __restrict__ hn,
                                                float* __restrict__ tau, int N) {
  int wave = threadIdx.x >> 6, lane = threadIdx.x & 63;
  int row = blockIdx.x * 4 + wave;
  const float4* hn4 = (const float4*)hn;
  float4 q[4];
#pragma unroll
  for (int m = 0; m < 4; ++m) q[m] = hn4[(size_t)row*4 + m];
  Top6 t; t6_init(t);
#pragma unroll
  for (int k = 0; k < SAMP/64; ++k) {
    int c = lane + 64*k;
    if (c != row) {
      float4 cv[4];
#pragma unroll
      for (int m = 0; m < 4; ++m) cv[m] = hn4[(size_t)c*4 + m];
      float s = dot16_seq(q, cv);
      t6_insert(t, s, c);
    }
  }
  float last = -1e30f;
  for (int sel = 0; sel < K; ++sel) {
    float cv; int ci;
    t6_best(t, cv, ci);
    float mv = cv; int mi = ci;
#pragma unroll
    for (int m = 1; m < 64; m <<= 1) {
      float ov = __shfl_xor(mv, m);
      int   oi = __shfl_xor(mi, m);
      if (ov > mv || (ov == mv && (unsigned)oi < (unsigned)mi)) { mv = ov; mi = oi; }
    }
    t6_consume(t, mi);
    last = mv;
  }
  if (lane == 0) tau[row] = last;
}

// ---------------- MFMA threshold scan, XCD-local appends ----------------
// One block owns 16 rows (ALL candidates) -> no cross-XCD line bouncing.
// 4 waves split candidates. Hits aggregated via ballot; counters in LDS
// (LDS atomics only); indices written by one lane per row-group.
__global__ __launch_bounds__(256) void k_scan2(
    const short* __restrict__ hnb, const float* __restrict__ tau,
    int* __restrict__ cnt, unsigned short* __restrict__ buf, int N) {
  __shared__ int cntl[16];
  int rb = blockIdx.x;               // N/16 row groups
  int wave = threadIdx.x >> 6, lane = threadIdx.x & 63;
  int r0 = rb * 16;
  int half = lane >> 4;              // 0..3
  int l16  = lane & 15;

  if (threadIdx.x < 16) cntl[threadIdx.x] = 0;
  __syncthreads();

  bf16x8 a = *(const bf16x8*)(hnb + (size_t)(r0 + l16)*32 + half*8);
  float4 t4 = *(const float4*)(tau + r0 + half*4);
  float tm0 = t4.x - MARGIN, tm1 = t4.y - MARGIN,
        tm2 = t4.z - MARGIN, tm3 = t4.w - MARGIN;
  int rowA = r0 + half*4;
  f32x4 zero = {0.f, 0.f, 0.f, 0.f};

  const int SPAN = N / 4;            // cands per wave (2048)
  int jb0 = wave * SPAN;

#define APPB(R, COND)                                                        \
  {                                                                          \
    unsigned long long mr = __ballot(COND);                                  \
    if (l16 == 0) {                                                          \
      unsigned mask = (unsigned)(mr >> (16*half)) & 0xFFFFu;                 \
      if (mask) {                                                            \
        int c = __popc(mask);                                                \
        int row = rowA + (R);                                                \
        int pos = atomicAdd(&cntl[4*half + (R)], c);                         \
        unsigned mm = mask;                                                  \
        while (mm) {                                                         \
          int bx = __ffs(mm) - 1; mm &= mm - 1;                              \
          if (pos < CAP) buf[(size_t)row*CAP + pos] = (unsigned short)(jb + bx); \
          ++pos;                                                             \
        }                                                                    \
      }                                                                      \
    }                                                                        \
  }

#pragma unroll 4
  for (int jt = 0; jt < SPAN; jt += 16) {
    int jb = jb0 + jt;
    bf16x8 b = *(const bf16x8*)(hnb + (size_t)(jb + l16)*32 + half*8);
    f32x4 d = __builtin_amdgcn_mfma_f32_16x16x32_bf16(a, b, zero, 0, 0, 0);
    APPB(0, d[0] >= tm0)
    APPB(1, d[1] >= tm1)
    APPB(2, d[2] >= tm2)
    APPB(3, d[3] >= tm3)
  }
#undef APPB

  __syncthreads();
  if (threadIdx.x < 16) cnt[r0 + threadIdx.x] = min(cntl[threadIdx.x], CAP);
}

// ---------------- exact top-6 from buffered candidates, wave per row ----
__global__ __launch_bounds__(256) void k_final(
    const float* __restrict__ hn, const unsigned short* __restrict__ buf,
    const int* __restrict__ cnt,
    float* __restrict__ evals, int* __restrict__ eidx,
    float* __restrict__ ownsum, float* insum, int* indeg, int N) {
  int wave = threadIdx.x >> 6, lane = threadIdx.x & 63;
  int row = blockIdx.x * 4 + wave;
  const float4* hn4 = (const float4*)hn;
  float4 q[4];
#pragma unroll
  for (int m = 0; m < 4; ++m) q[m] = hn4[(size_t)row*4 + m];
  int n = cnt[row];
  Top6 t; t6_init(t);
  for (int e = lane; e < n; e += 64) {
    int j = buf[(size_t)row*CAP + e];
    if (j != row) {
      float4 cv[4];
#pragma unroll
      for (int m = 0; m < 4; ++m) cv[m] = hn4[(size_t)j*4 + m];
      float s = dot16_seq(q, cv);
      t6_insert(t, s, j);
    }
  }
  float osum = 0.f;
  for (int sel = 0; sel < K; ++sel) {
    float cv; int ci;
    t6_best(t, cv, ci);
    float mv = cv; int mi = ci;
#pragma unroll
    for (int m = 1; m < 64; m <<= 1) {
      float ov = __shfl_xor(mv, m);
      int   oi = __shfl_xor(mi, m);
      if (ov > mv || (ov == mv && (unsigned)oi < (unsigned)mi)) { mv = ov; mi = oi; }
    }
    t6_consume(t, mi);
    if (lane == 0) {
      evals[row*K + sel] = mv;
      eidx [row*K + sel] = mi;
      osum += mv;
      atomicAdd(&insum[mi], mv);
      atomicAdd(&indeg[mi], 1);
    }
  }
  if (lane == 0) ownsum[row] = osum;
}

// ------- fused: degree scalars + exclusive scan of (K + indeg) -> CSR offsets ----
__global__ __launch_bounds__(1024) void k_scan(
    const int* __restrict__ indeg, const float* __restrict__ ownsum,
    const float* __restrict__ insum,
    float* __restrict__ rnorm, float* __restrict__ dinv, float* __restrict__ selfc,
    int* __restrict__ cursor, int* __restrict__ offsets, int N) {
  __shared__ int sums[1024];
  int tid = threadIdx.x;
  int per = N >> 10;           // assumes N multiple of 1024
  int base = tid * per;
  int loc[16];
  int s = 0;
  for (int k = 0; k < per; ++k) {
    int i = base + k;
    float rs = 0.5f * (ownsum[i] + insum[i]);
    float rn = 1.f / (rs + 1e-8f);
    float ds = 1.f + rs * rn;
    float di = rsqrtf(fmaxf(ds, 1e-12f));
    rnorm[i] = rn; dinv[i] = di; selfc[i] = di * di; cursor[i] = 0;
    loc[k] = s; s += K + indeg[i];
  }
  sums[tid] = s;
  __syncthreads();
  for (int d = 1; d < 1024; d <<= 1) {
    int v = (tid >= d) ? sums[tid - d] : 0;
    __syncthreads();
    sums[tid] += v;
    __syncthreads();
  }
  int excl = (tid == 0) ? 0 : sums[tid - 1];
  for (int k = 0; k < per; ++k) offsets[base + k] = excl + loc[k];
  if (tid == 1023) offsets[N] = sums[1023];
}

// ---------------- fill symmetrized CSR with fused coefficients ----------------
__global__ void k_fill(const float* __restrict__ evals, const int* __restrict__ eidx,
                       const float* __restrict__ rnorm, const float* __restrict__ dinv,
                       const int* __restrict__ offsets, int* cursor,
                       int* __restrict__ col, float* __restrict__ coef, int N) {
  int e = blockIdx.x * blockDim.x + threadIdx.x;
  if (e >= N * K) return;
  int i = e / K;
  int j = eidx[e];
  float v = evals[e];
  float base = 0.5f * v * dinv[i] * dinv[j];
  int p = atomicAdd(&cursor[i], 1);
  col [offsets[i] + p] = j;
  coef[offsets[i] + p] = base * rnorm[i];
  int q = atomicAdd(&cursor[j], 1);
  col [offsets[j] + q] = i;
  coef[offsets[j] + q] = base * rnorm[j];
}

// ---------------- dense h @ W ----------------
template<int DIN, int DOUT>
__global__ void k_xw(const float* __restrict__ h, const float* __restrict__ W,
                     float* __restrict__ XW, int N) {
  int gid = blockIdx.x * blockDim.x + threadIdx.x;
  if (gid >= N * DOUT) return;
  int oc = gid % DOUT;
  int i  = gid / DOUT;
  float acc = 0.f;
#pragma unroll
  for (int d = 0; d < DIN; ++d) acc += h[i*DIN + d] * W[d*DOUT + oc];
  XW[gid] = acc;
}

// ---------------- fused: sparse gather + bias + LN + relu + MLP residual ----------------
template<int DIN, int HID, int DOUT>
__global__ __launch_bounds__(256) void k_gpost(
    const float* __restrict__ XW, const int* __restrict__ offsets,
    const int* __restrict__ col, const float* __restrict__ coef,
    const float* __restrict__ selfc,
    const float* __restrict__ b, const float* __restrict__ g, const float* __restrict__ bt,
    const float* __restrict__ hprev,
    const float* __restrict__ w0, const float* __restrict__ b0,
    const float* __restrict__ w1, const float* __restrict__ b1,
    float* __restrict__ out, int N) {
  __shared__ float hid_s[4][HID];
  int wslot = threadIdx.x >> 6;
  int row   = (blockIdx.x * blockDim.x + threadIdx.x) >> 6;
  int lane  = threadIdx.x & 63;
  int o0 = lane, o1 = lane + 64;

  float sc = selfc[row];
  float acc0 = 0.f, acc1 = 0.f;
  if (o0 < DOUT)  acc0 = sc * XW[(size_t)row*DOUT + o0];
  if (DOUT > 64)  acc1 = sc * XW[(size_t)row*DOUT + o1];
  int pe = offsets[row + 1];
  for (int p = offsets[row]; p < pe; ++p) {
    int jj = col[p]; float cf = coef[p];
    if (o0 < DOUT) acc0 += cf * XW[(size_t)jj*DOUT + o0];
    if (DOUT > 64) acc1 += cf * XW[(size_t)jj*DOUT + o1];
  }
  float u0 = (o0 < DOUT) ? acc0 + b[o0] : 0.f;
  float u1 = (DOUT > 64) ? acc1 + b[o1] : 0.f;

  float s = u0 + u1;
#pragma unroll
  for (int m = 1; m < 64; m <<= 1) s += __shfl_xor(s, m);
  float mean = s / (float)DOUT;
  float d0 = (o0 < DOUT) ? u0 - mean : 0.f;
  float d1 = (DOUT > 64) ? u1 - mean : 0.f;
  float vs = d0*d0 + d1*d1;
#pragma unroll
  for (int m = 1; m < 64; m <<= 1) vs += __shfl_xor(vs, m);
  float rstd = rsqrtf(vs / (float)DOUT + 1e-5f);
  float t0 = (o0 < DOUT) ? fmaxf(d0*rstd*g[o0] + bt[o0], 0.f) : 0.f;
  float t1 = (DOUT > 64) ? fmaxf(d1*rstd*g[o1] + bt[o1], 0.f) : 0.f;

  // MLP hidden = relu(hprev @ w0 + b0), staged in LDS per wave
  float hp[DIN];
#pragma unroll
  for (int d = 0; d < DIN; ++d) hp[d] = hprev[(size_t)row*DIN + d];
  if (lane < HID) {
    float a = b0[lane];
#pragma unroll
    for (int d = 0; d < DIN; ++d) a += hp[d] * w0[d*HID + lane];
    hid_s[wslot][lane] = fmaxf(a, 0.f);
  }
  if (HID > 64) {
    int h2i = lane + 64;
    float a = b0[h2i];
#pragma unroll
    for (int d = 0; d < DIN; ++d) a += hp[d] * w0[d*HID + h2i];
    hid_s[wslot][h2i] = fmaxf(a, 0.f);
  }
  __syncthreads();

  if (o0 < DOUT) {
    float a = b1[o0];
    for (int h = 0; h < HID; ++h) a += hid_s[wslot][h] * w1[h*DOUT + o0];
    out[(size_t)row*DOUT + o0] = t0 + a;
  }
  if (DOUT > 64) {
    float a = b1[o1];
    for (int h = 0; h < HID; ++h) a += hid_s[wslot][h] * w1[h*DOUT + o1];
    out[(size_t)row*DOUT + o1] = t1 + a;
  }
}

extern "C" void kernel_launch(void* const* d_in, const int* in_sizes, int n_in,
                              void* d_out, int out_size, void* d_ws, size_t ws_size,
                              hipStream_t stream) {
  const float* x    = (const float*)d_in[0];
  const float* Wp   = (const float*)d_in[1];
  const float* bp   = (const float*)d_in[2];
  const float* gw0  = (const float*)d_in[3];
  const float* gb0  = (const float*)d_in[4];
  const float* gw1  = (const float*)d_in[5];
  const float* gb1  = (const float*)d_in[6];
  const float* gw2  = (const float*)d_in[7];
  const float* gb2  = (const float*)d_in[8];
  const float* lg0  = (const float*)d_in[9];
  const float* lb0  = (const float*)d_in[10];
  const float* lg1  = (const float*)d_in[11];
  const float* lb1  = (const float*)d_in[12];
  const float* lg2  = (const float*)d_in[13];
  const float* lb2  = (const float*)d_in[14];
  const float* riw0 = (const float*)d_in[15];
  const float* rib0 = (const float*)d_in[16];
  const float* riw1 = (const float*)d_in[17];
  const float* rib1 = (const float*)d_in[18];
  const float* rhw0 = (const float*)d_in[19];
  const float* rhb0 = (const float*)d_in[20];
  const float* rhw1 = (const float*)d_in[21];
  const float* rhb1 = (const float*)d_in[22];
  const float* row0 = (const float*)d_in[23];
  const float* rob0 = (const float*)d_in[24];
  const float* row1 = (const float*)d_in[25];
  const float* rob1 = (const float*)d_in[26];
  int N = in_sizes[0] / D_IN;   // 8192
  float* out = (float*)d_out;

  char* ws = (char*)d_ws;
  size_t off = 0;
  auto alloc = [&](size_t bytes) -> void* {
    void* p = ws + off;
    off += (bytes + 255) & ~(size_t)255;
    return p;
  };
  float* hn      = (float*)alloc((size_t)N * HP * 4);
  float* evals   = (float*)alloc((size_t)N * K * 4);
  int*   eidx    = (int*)  alloc((size_t)N * K * 4);
  float* ownsum  = (float*)alloc((size_t)N * 4);
  float* insum   = (float*)alloc((size_t)N * 4);
  int*   indeg   = (int*)  alloc((size_t)N * 4);
  float* rnorm   = (float*)alloc((size_t)N * 4);
  float* dinv    = (float*)alloc((size_t)N * 4);
  float* selfc   = (float*)alloc((size_t)N * 4);
  int*   offsets = (int*)  alloc((size_t)(N + 1) * 4);
  int*   cursor  = (int*)  alloc((size_t)N * 4);
  int*   colA    = (int*)  alloc((size_t)N * K * 2 * 4);
  float* coefA   = (float*)alloc((size_t)N * K * 2 * 4);
  float* XW      = (float*)alloc((size_t)N * 128 * 4);
  float* h1      = (float*)alloc((size_t)N * 32 * 4);
  float* h2      = (float*)alloc((size_t)N * 32 * 4);
  float* tau     = (float*)alloc((size_t)N * 4);
  int*   cnt     = (int*)  alloc((size_t)N * 4);
  unsigned short* buf = (unsigned short*)alloc((size_t)N * CAP * 2);
  short* hnb     = (short*)alloc((size_t)N * 32 * 2);
  (void)ws_size; (void)n_in; (void)out_size;

  const int B = 256;
  hipLaunchKernelGGL(k_proj, dim3((N + B - 1) / B), dim3(B), 0, stream,
                     x, Wp, bp, gw0, hn, hnb, XW, insum, indeg, N);
  hipLaunchKernelGGL(k_thresh, dim3(N / 4), dim3(B), 0, stream, hn, tau, N);
  // one block per 16-row group owns ALL candidates (XCD-local appends)
  hipLaunchKernelGGL(k_scan2, dim3(N / 16), dim3(B), 0, stream, hnb, tau, cnt, buf, N);
  hipLaunchKernelGGL(k_final, dim3(N / 4), dim3(B), 0, stream,
                     hn, buf, cnt, evals, eidx, ownsum, insum, indeg, N);
  hipLaunchKernelGGL(k_scan, dim3(1), dim3(1024), 0, stream,
                     indeg, ownsum, insum, rnorm, dinv, selfc, cursor, offsets, N);
  hipLaunchKernelGGL(k_fill, dim3((N * K + B - 1) / B), dim3(B), 0, stream,
                     evals, eidx, rnorm, dinv, offsets, cursor, colA, coefA, N);

  // layer 0: XW0 precomputed in k_proj
  hipLaunchKernelGGL((k_gpost<20, 32, 32>), dim3(N / 4), dim3(B), 0, stream,
                     XW, offsets, colA, coefA, selfc, gb0, lg0, lb0,
                     x, riw0, rib0, riw1, rib1, h1, N);
  // layer 1: h1[32] -> 32
  hipLaunchKernelGGL((k_xw<32, 32>), dim3((N * 32 + B - 1) / B), dim3(B), 0, stream, h1, gw1, XW, N);
  hipLaunchKernelGGL((k_gpost<32, 32, 32>), dim3(N / 4), dim3(B), 0, stream,
                     XW, offsets, colA, coefA, selfc, gb1, lg1, lb1,
                     h1, rhw0, rhb0, rhw1, rhb1, h2, N);
  // layer 2: h2[32] -> 128
  hipLaunchKernelGGL((k_xw<32, 128>), dim3((N * 128 + B - 1) / B), dim3(B), 0, stream, h2, gw2, XW, N);
  hipLaunchKernelGGL((k_gpost<32, 128, 128>), dim3(N / 4), dim3(B), 0, stream,
                     XW, offsets, colA, coefA, selfc, gb2, lg2, lb2,
                     h2, row0, rob0, row1, rob1, out, N);
}

// Round 12
// 213.501 us; speedup vs baseline: 1.2178x; 1.2178x over previous
//
#include <hip/hip_runtime.h>

constexpr int D_IN = 20;   // input feature dim
constexpr int HP   = 16;   // projection dim
constexpr int K    = 6;    // neighbors
constexpr int SAMP = 512;  // threshold sample size
constexpr int NC   = 8;    // candidate chunks (segmented buffers)
constexpr int CAPC = 192;  // per-(row,chunk) buffer capacity (exp ~12 hits)
constexpr float MARGIN = 0.02f;  // covers bf16-vs-fp32 dot error (<=~0.008)

typedef __attribute__((ext_vector_type(8))) short bf16x8;
typedef __attribute__((ext_vector_type(4))) float f32x4;

// Sequential fmaf dot — MUST be bit-identical across thresh/final.
__device__ __forceinline__ float dot16_seq(const float4* q, const float4* c) {
  float s = 0.f;
#pragma unroll
  for (int m = 0; m < 4; ++m) {
    s = fmaf(q[m].x, c[m].x, s);
    s = fmaf(q[m].y, c[m].y, s);
    s = fmaf(q[m].z, c[m].z, s);
    s = fmaf(q[m].w, c[m].w, s);
  }
  return s;
}

// round-to-nearest-even f32 -> bf16 bits
__device__ __forceinline__ short f2bf(float f) {
  unsigned u = __float_as_uint(f);
  unsigned r = (u + 0x7fffu + ((u >> 16) & 1u)) >> 16;
  return (short)r;
}

// ---- projection + row-normalize + bf16 copy + XW0 + counter zeroing ----
__global__ void k_proj(const float* __restrict__ x, const float* __restrict__ Wp,
                       const float* __restrict__ bp, const float* __restrict__ gw0,
                       float* __restrict__ hn, short* __restrict__ hnb,
                       float* __restrict__ XW0,
                       float* __restrict__ insum, int* __restrict__ indeg, int N) {
  int i = blockIdx.x * blockDim.x + threadIdx.x;
  if (i >= N) return;
  insum[i] = 0.f; indeg[i] = 0;
  float xr[D_IN];
#pragma unroll
  for (int d = 0; d < D_IN; ++d) xr[d] = x[i*D_IN + d];
  float hv[HP];
  float nrm2 = 0.f;
#pragma unroll
  for (int h = 0; h < HP; ++h) {
    float a = bp[h];
#pragma unroll
    for (int d = 0; d < D_IN; ++d) a += xr[d] * Wp[d*HP + h];
    hv[h] = a;
    nrm2 += a * a;
  }
  float inv = 1.f / fmaxf(sqrtf(nrm2), 1e-12f);
#pragma unroll
  for (int h = 0; h < HP; ++h) {
    float v = hv[h] * inv;
    hn[i*HP + h] = v;
    hnb[(size_t)i*32 + h] = f2bf(v);
  }
#pragma unroll
  for (int h = 0; h < HP; ++h) hnb[(size_t)i*32 + 16 + h] = 0;
  // fused XW0 = x @ gw0 (bias added in k_gpost)
#pragma unroll
  for (int oc = 0; oc < 32; ++oc) {
    float a = 0.f;
#pragma unroll
    for (int d = 0; d < D_IN; ++d) a += xr[d] * gw0[d*32 + oc];
    XW0[(size_t)i*32 + oc] = a;
  }
}

// ---------------- per-lane top-6 in NAMED registers ----
struct Top6 { float v0,v1,v2,v3,v4,v5; int i0,i1,i2,i3,i4,i5; };

__device__ __forceinline__ void t6_init(Top6& t) {
  t.v0=t.v1=t.v2=t.v3=t.v4=t.v5=-1e30f;
  t.i0=t.i1=t.i2=t.i3=t.i4=t.i5=-1;
}

#define T6_SWAP(a,b,ia,ib) { float tv=a; a=b; b=tv; int ti=ia; ia=ib; ib=ti; }

__device__ __forceinline__ void t6_insert(Top6& t, float s, int c) {
  if (s > t.v5) {
    t.v5 = s; t.i5 = c;
    if (t.v5 > t.v4) { T6_SWAP(t.v4, t.v5, t.i4, t.i5); }
    if (t.v4 > t.v3) { T6_SWAP(t.v3, t.v4, t.i3, t.i4); }
    if (t.v3 > t.v2) { T6_SWAP(t.v2, t.v3, t.i2, t.i3); }
    if (t.v2 > t.v1) { T6_SWAP(t.v1, t.v2, t.i1, t.i2); }
    if (t.v1 > t.v0) { T6_SWAP(t.v0, t.v1, t.i0, t.i1); }
  }
}

__device__ __forceinline__ void t6_best(const Top6& t, float& cv, int& ci) {
  cv = t.v0; ci = t.i0;
  if (t.v1 > cv || (t.v1 == cv && (unsigned)t.i1 < (unsigned)ci)) { cv = t.v1; ci = t.i1; }
  if (t.v2 > cv || (t.v2 == cv && (unsigned)t.i2 < (unsigned)ci)) { cv = t.v2; ci = t.i2; }
  if (t.v3 > cv || (t.v3 == cv && (unsigned)t.i3 < (unsigned)ci)) { cv = t.v3; ci = t.i3; }
  if (t.v4 > cv || (t.v4 == cv && (unsigned)t.i4 < (unsigned)ci)) { cv = t.v4; ci = t.i4; }
  if (t.v5 > cv || (t.v5 == cv && (unsigned)t.i5 < (unsigned)ci)) { cv = t.v5; ci = t.i5; }
}

__device__ __forceinline__ void t6_consume(Top6& t, int mi) {
  if (t.i0 == mi) t.v0 = -1e30f;
  if (t.i1 == mi) t.v1 = -1e30f;
  if (t.i2 == mi) t.v2 = -1e30f;
  if (t.i3 == mi) t.v3 = -1e30f;
  if (t.i4 == mi) t.v4 = -1e30f;
  if (t.i5 == mi) t.v5 = -1e30f;
}

// ---------------- threshold pass: exact 6th-largest over SAMP-sample, wave per row
__global__ __launch_bounds__(256) void k_thresh(const float* __restrict__ hn,
                                                float* __restrict__ tau, int N) {
  int wave = threadIdx.x >> 6, lane = threadIdx.x & 63;
  int row = blockIdx.x * 4 + wave;
  const float4* hn4 = (const float4*)hn;
  float4 q[4];
#pragma unroll
  for (int m = 0; m < 4; ++m) q[m] = hn4[(size_t)row*4 + m];
  Top6 t; t6_init(t);
#pragma unroll
  for (int k = 0; k < SAMP/64; ++k) {
    int c = lane + 64*k;
    if (c != row) {
      float4 cv[4];
#pragma unroll
      for (int m = 0; m < 4; ++m) cv[m] = hn4[(size_t)c*4 + m];
      float s = dot16_seq(q, cv);
      t6_insert(t, s, c);
    }
  }
  float last = -1e30f;
  for (int sel = 0; sel < K; ++sel) {
    float cv; int ci;
    t6_best(t, cv, ci);
    float mv = cv; int mi = ci;
#pragma unroll
    for (int m = 1; m < 64; m <<= 1) {
      float ov = __shfl_xor(mv, m);
      int   oi = __shfl_xor(mi, m);
      if (ov > mv || (ov == mv && (unsigned)oi < (unsigned)mi)) { mv = ov; mi = oi; }
    }
    t6_consume(t, mi);
    last = mv;
  }
  if (lane == 0) tau[row] = last;
}

// ---------------- MFMA threshold scan: segmented XCD-local appends ----------------
// Grid (N/16) x NC: block owns 16 rows x (N/NC) candidates -> its own buf/cnt
// segments (no cross-block sharing). LDS counters only. Ballot-aggregated writes.
__global__ __launch_bounds__(256) void k_scan2(
    const short* __restrict__ hnb, const float* __restrict__ tau,
    int* __restrict__ cnt, unsigned short* __restrict__ buf, int N) {
  __shared__ int cntl[16];
  int rb = blockIdx.x / NC;          // row group
  int jc = blockIdx.x % NC;          // candidate chunk
  int wave = threadIdx.x >> 6, lane = threadIdx.x & 63;
  int r0 = rb * 16;
  int half = lane >> 4;              // 0..3
  int l16  = lane & 15;

  if (threadIdx.x < 16) cntl[threadIdx.x] = 0;
  __syncthreads();

  bf16x8 a = *(const bf16x8*)(hnb + (size_t)(r0 + l16)*32 + half*8);
  float4 t4 = *(const float4*)(tau + r0 + half*4);
  float tm0 = t4.x - MARGIN, tm1 = t4.y - MARGIN,
        tm2 = t4.z - MARGIN, tm3 = t4.w - MARGIN;
  f32x4 zero = {0.f, 0.f, 0.f, 0.f};

  const int SPAN = N / NC / 4;       // cands per wave (256)
  int jb0 = jc * (N / NC) + wave * SPAN;

#define APPB(R, COND)                                                        \
  {                                                                          \
    unsigned long long mr = __ballot(COND);                                  \
    if (l16 == 0) {                                                          \
      unsigned mask = (unsigned)(mr >> (16*half)) & 0xFFFFu;                 \
      if (mask) {                                                            \
        int row = r0 + half*4 + (R);                                         \
        int pos = atomicAdd(&cntl[4*half + (R)], __popc(mask));              \
        unsigned mm = mask;                                                  \
        while (mm) {                                                         \
          int bx = __ffs(mm) - 1; mm &= mm - 1;                              \
          if (pos < CAPC)                                                    \
            buf[((size_t)row*NC + jc)*CAPC + pos] = (unsigned short)(jb + bx); \
          ++pos;                                                             \
        }                                                                    \
      }                                                                      \
    }                                                                        \
  }

#pragma unroll 4
  for (int jt = 0; jt < SPAN; jt += 16) {
    int jb = jb0 + jt;
    bf16x8 b = *(const bf16x8*)(hnb + (size_t)(jb + l16)*32 + half*8);
    f32x4 d = __builtin_amdgcn_mfma_f32_16x16x32_bf16(a, b, zero, 0, 0, 0);
    bool h0 = d[0] >= tm0, h1 = d[1] >= tm1, h2 = d[2] >= tm2, h3 = d[3] >= tm3;
    if (__any(h0 | h1 | h2 | h3)) {
      APPB(0, h0)
      APPB(1, h1)
      APPB(2, h2)
      APPB(3, h3)
    }
  }
#undef APPB

  __syncthreads();
  if (threadIdx.x < 16)
    cnt[(size_t)(r0 + threadIdx.x)*NC + jc] = min(cntl[threadIdx.x], CAPC);
}

// ---------------- exact top-6 from segmented candidates, wave per row ----
__global__ __launch_bounds__(256) void k_final(
    const float* __restrict__ hn, const unsigned short* __restrict__ buf,
    const int* __restrict__ cnt,
    float* __restrict__ evals, int* __restrict__ eidx,
    float* __restrict__ ownsum, float* insum, int* indeg, int N) {
  int wave = threadIdx.x >> 6, lane = threadIdx.x & 63;
  int row = blockIdx.x * 4 + wave;
  const float4* hn4 = (const float4*)hn;
  float4 q[4];
#pragma unroll
  for (int m = 0; m < 4; ++m) q[m] = hn4[(size_t)row*4 + m];
  Top6 t; t6_init(t);
#pragma unroll
  for (int jc = 0; jc < NC; ++jc) {
    int nseg = cnt[(size_t)row*NC + jc];
    const unsigned short* seg = buf + ((size_t)row*NC + jc)*CAPC;
    for (int e = lane; e < nseg; e += 64) {
      int j = seg[e];
      if (j != row) {
        float4 cv[4];
#pragma unroll
        for (int m = 0; m < 4; ++m) cv[m] = hn4[(size_t)j*4 + m];
        float s = dot16_seq(q, cv);
        t6_insert(t, s, j);
      }
    }
  }
  float osum = 0.f;
  for (int sel = 0; sel < K; ++sel) {
    float cv; int ci;
    t6_best(t, cv, ci);
    float mv = cv; int mi = ci;
#pragma unroll
    for (int m = 1; m < 64; m <<= 1) {
      float ov = __shfl_xor(mv, m);
      int   oi = __shfl_xor(mi, m);
      if (ov > mv || (ov == mv && (unsigned)oi < (unsigned)mi)) { mv = ov; mi = oi; }
    }
    t6_consume(t, mi);
    if (lane == 0) {
      evals[row*K + sel] = mv;
      eidx [row*K + sel] = mi;
      osum += mv;
      atomicAdd(&insum[mi], mv);
      atomicAdd(&indeg[mi], 1);
    }
  }
  if (lane == 0) ownsum[row] = osum;
}

// ------- fused: degree scalars + exclusive scan of (K + indeg) -> CSR offsets ----
__global__ __launch_bounds__(1024) void k_scan(
    const int* __restrict__ indeg, const float* __restrict__ ownsum,
    const float* __restrict__ insum,
    float* __restrict__ rnorm, float* __restrict__ dinv, float* __restrict__ selfc,
    int* __restrict__ cursor, int* __restrict__ offsets, int N) {
  __shared__ int sums[1024];
  int tid = threadIdx.x;
  int per = N >> 10;           // assumes N multiple of 1024
  int base = tid * per;
  int loc[16];
  int s = 0;
  for (int k = 0; k < per; ++k) {
    int i = base + k;
    float rs = 0.5f * (ownsum[i] + insum[i]);
    float rn = 1.f / (rs + 1e-8f);
    float ds = 1.f + rs * rn;
    float di = rsqrtf(fmaxf(ds, 1e-12f));
    rnorm[i] = rn; dinv[i] = di; selfc[i] = di * di; cursor[i] = 0;
    loc[k] = s; s += K + indeg[i];
  }
  sums[tid] = s;
  __syncthreads();
  for (int d = 1; d < 1024; d <<= 1) {
    int v = (tid >= d) ? sums[tid - d] : 0;
    __syncthreads();
    sums[tid] += v;
    __syncthreads();
  }
  int excl = (tid == 0) ? 0 : sums[tid - 1];
  for (int k = 0; k < per; ++k) offsets[base + k] = excl + loc[k];
  if (tid == 1023) offsets[N] = sums[1023];
}

// ---------------- fill symmetrized CSR with fused coefficients ----------------
__global__ void k_fill(const float* __restrict__ evals, const int* __restrict__ eidx,
                       const float* __restrict__ rnorm, const float* __restrict__ dinv,
                       const int* __restrict__ offsets, int* cursor,
                       int* __restrict__ col, float* __restrict__ coef, int N) {
  int e = blockIdx.x * blockDim.x + threadIdx.x;
  if (e >= N * K) return;
  int i = e / K;
  int j = eidx[e];
  float v = evals[e];
  float base = 0.5f * v * dinv[i] * dinv[j];
  int p = atomicAdd(&cursor[i], 1);
  col [offsets[i] + p] = j;
  coef[offsets[i] + p] = base * rnorm[i];
  int q = atomicAdd(&cursor[j], 1);
  col [offsets[j] + q] = i;
  coef[offsets[j] + q] = base * rnorm[j];
}

// ---------------- dense h @ W ----------------
template<int DIN, int DOUT>
__global__ void k_xw(const float* __restrict__ h, const float* __restrict__ W,
                     float* __restrict__ XW, int N) {
  int gid = blockIdx.x * blockDim.x + threadIdx.x;
  if (gid >= N * DOUT) return;
  int oc = gid % DOUT;
  int i  = gid / DOUT;
  float acc = 0.f;
#pragma unroll
  for (int d = 0; d < DIN; ++d) acc += h[i*DIN + d] * W[d*DOUT + oc];
  XW[gid] = acc;
}

// ---------------- fused: sparse gather + bias + LN + relu + MLP residual ----------------
template<int DIN, int HID, int DOUT>
__global__ __launch_bounds__(256) void k_gpost(
    const float* __restrict__ XW, const int* __restrict__ offsets,
    const int* __restrict__ col, const float* __restrict__ coef,
    const float* __restrict__ selfc,
    const float* __restrict__ b, const float* __restrict__ g, const float* __restrict__ bt,
    const float* __restrict__ hprev,
    const float* __restrict__ w0, const float* __restrict__ b0,
    const float* __restrict__ w1, const float* __restrict__ b1,
    float* __restrict__ out, int N) {
  __shared__ float hid_s[4][HID];
  int wslot = threadIdx.x >> 6;
  int row   = (blockIdx.x * blockDim.x + threadIdx.x) >> 6;
  int lane  = threadIdx.x & 63;
  int o0 = lane, o1 = lane + 64;

  float sc = selfc[row];
  float acc0 = 0.f, acc1 = 0.f;
  if (o0 < DOUT)  acc0 = sc * XW[(size_t)row*DOUT + o0];
  if (DOUT > 64)  acc1 = sc * XW[(size_t)row*DOUT + o1];
  int pe = offsets[row + 1];
  for (int p = offsets[row]; p < pe; ++p) {
    int jj = col[p]; float cf = coef[p];
    if (o0 < DOUT) acc0 += cf * XW[(size_t)jj*DOUT + o0];
    if (DOUT > 64) acc1 += cf * XW[(size_t)jj*DOUT + o1];
  }
  float u0 = (o0 < DOUT) ? acc0 + b[o0] : 0.f;
  float u1 = (DOUT > 64) ? acc1 + b[o1] : 0.f;

  float s = u0 + u1;
#pragma unroll
  for (int m = 1; m < 64; m <<= 1) s += __shfl_xor(s, m);
  float mean = s / (float)DOUT;
  float d0 = (o0 < DOUT) ? u0 - mean : 0.f;
  float d1 = (DOUT > 64) ? u1 - mean : 0.f;
  float vs = d0*d0 + d1*d1;
#pragma unroll
  for (int m = 1; m < 64; m <<= 1) vs += __shfl_xor(vs, m);
  float rstd = rsqrtf(vs / (float)DOUT + 1e-5f);
  float t0 = (o0 < DOUT) ? fmaxf(d0*rstd*g[o0] + bt[o0], 0.f) : 0.f;
  float t1 = (DOUT > 64) ? fmaxf(d1*rstd*g[o1] + bt[o1], 0.f) : 0.f;

  // MLP hidden = relu(hprev @ w0 + b0), staged in LDS per wave
  float hp[DIN];
#pragma unroll
  for (int d = 0; d < DIN; ++d) hp[d] = hprev[(size_t)row*DIN + d];
  if (lane < HID) {
    float a = b0[lane];
#pragma unroll
    for (int d = 0; d < DIN; ++d) a += hp[d] * w0[d*HID + lane];
    hid_s[wslot][lane] = fmaxf(a, 0.f);
  }
  if (HID > 64) {
    int h2i = lane + 64;
    float a = b0[h2i];
#pragma unroll
    for (int d = 0; d < DIN; ++d) a += hp[d] * w0[d*HID + h2i];
    hid_s[wslot][h2i] = fmaxf(a, 0.f);
  }
  __syncthreads();

  if (o0 < DOUT) {
    float a = b1[o0];
    for (int h = 0; h < HID; ++h) a += hid_s[wslot][h] * w1[h*DOUT + o0];
    out[(size_t)row*DOUT + o0] = t0 + a;
  }
  if (DOUT > 64) {
    float a = b1[o1];
    for (int h = 0; h < HID; ++h) a += hid_s[wslot][h] * w1[h*DOUT + o1];
    out[(size_t)row*DOUT + o1] = t1 + a;
  }
}

extern "C" void kernel_launch(void* const* d_in, const int* in_sizes, int n_in,
                              void* d_out, int out_size, void* d_ws, size_t ws_size,
                              hipStream_t stream) {
  const float* x    = (const float*)d_in[0];
  const float* Wp   = (const float*)d_in[1];
  const float* bp   = (const float*)d_in[2];
  const float* gw0  = (const float*)d_in[3];
  const float* gb0  = (const float*)d_in[4];
  const float* gw1  = (const float*)d_in[5];
  const float* gb1  = (const float*)d_in[6];
  const float* gw2  = (const float*)d_in[7];
  const float* gb2  = (const float*)d_in[8];
  const float* lg0  = (const float*)d_in[9];
  const float* lb0  = (const float*)d_in[10];
  const float* lg1  = (const float*)d_in[11];
  const float* lb1  = (const float*)d_in[12];
  const float* lg2  = (const float*)d_in[13];
  const float* lb2  = (const float*)d_in[14];
  const float* riw0 = (const float*)d_in[15];
  const float* rib0 = (const float*)d_in[16];
  const float* riw1 = (const float*)d_in[17];
  const float* rib1 = (const float*)d_in[18];
  const float* rhw0 = (const float*)d_in[19];
  const float* rhb0 = (const float*)d_in[20];
  const float* rhw1 = (const float*)d_in[21];
  const float* rhb1 = (const float*)d_in[22];
  const float* row0 = (const float*)d_in[23];
  const float* rob0 = (const float*)d_in[24];
  const float* row1 = (const float*)d_in[25];
  const float* rob1 = (const float*)d_in[26];
  int N = in_sizes[0] / D_IN;   // 8192
  float* out = (float*)d_out;

  char* ws = (char*)d_ws;
  size_t off = 0;
  auto alloc = [&](size_t bytes) -> void* {
    void* p = ws + off;
    off += (bytes + 255) & ~(size_t)255;
    return p;
  };
  float* hn      = (float*)alloc((size_t)N * HP * 4);
  float* evals   = (float*)alloc((size_t)N * K * 4);
  int*   eidx    = (int*)  alloc((size_t)N * K * 4);
  float* ownsum  = (float*)alloc((size_t)N * 4);
  float* insum   = (float*)alloc((size_t)N * 4);
  int*   indeg   = (int*)  alloc((size_t)N * 4);
  float* rnorm   = (float*)alloc((size_t)N * 4);
  float* dinv    = (float*)alloc((size_t)N * 4);
  float* selfc   = (float*)alloc((size_t)N * 4);
  int*   offsets = (int*)  alloc((size_t)(N + 1) * 4);
  int*   cursor  = (int*)  alloc((size_t)N * 4);
  int*   colA    = (int*)  alloc((size_t)N * K * 2 * 4);
  float* coefA   = (float*)alloc((size_t)N * K * 2 * 4);
  float* XW      = (float*)alloc((size_t)N * 128 * 4);
  float* h1      = (float*)alloc((size_t)N * 32 * 4);
  float* h2      = (float*)alloc((size_t)N * 32 * 4);
  float* tau     = (float*)alloc((size_t)N * 4);
  int*   cnt     = (int*)  alloc((size_t)N * NC * 4);
  unsigned short* buf = (unsigned short*)alloc((size_t)N * NC * CAPC * 2);
  short* hnb     = (short*)alloc((size_t)N * 32 * 2);
  (void)ws_size; (void)n_in; (void)out_size;

  const int B = 256;
  hipLaunchKernelGGL(k_proj, dim3((N + B - 1) / B), dim3(B), 0, stream,
                     x, Wp, bp, gw0, hn, hnb, XW, insum, indeg, N);
  hipLaunchKernelGGL(k_thresh, dim3(N / 4), dim3(B), 0, stream, hn, tau, N);
  // (N/16) row groups x NC chunks; block owns private buf/cnt segments
  hipLaunchKernelGGL(k_scan2, dim3((N / 16) * NC), dim3(B), 0, stream, hnb, tau, cnt, buf, N);
  hipLaunchKernelGGL(k_final, dim3(N / 4), dim3(B), 0, stream,
                     hn, buf, cnt, evals, eidx, ownsum, insum, indeg, N);
  hipLaunchKernelGGL(k_scan, dim3(1), dim3(1024), 0, stream,
                     indeg, ownsum, insum, rnorm, dinv, selfc, cursor, offsets, N);
  hipLaunchKernelGGL(k_fill, dim3((N * K + B - 1) / B), dim3(B), 0, stream,
                     evals, eidx, rnorm, dinv, offsets, cursor, colA, coefA, N);

  // layer 0: XW0 precomputed in k_proj
  hipLaunchKernelGGL((k_gpost<20, 32, 32>), dim3(N / 4), dim3(B), 0, stream,
                     XW, offsets, colA, coefA, selfc, gb0, lg0, lb0,
                     x, riw0, rib0, riw1, rib1, h1, N);
  // layer 1: h1[32] -> 32
  hipLaunchKernelGGL((k_xw<32, 32>), dim3((N * 32 + B - 1) / B), dim3(B), 0, stream, h1, gw1, XW, N);
  hipLaunchKernelGGL((k_gpost<32, 32, 32>), dim3(N / 4), dim3(B), 0, stream,
                     XW, offsets, colA, coefA, selfc, gb1, lg1, lb1,
                     h1, rhw0, rhb0, rhw1, rhb1, h2, N);
  // layer 2: h2[32] -> 128
  hipLaunchKernelGGL((k_xw<32, 128>), dim3((N * 128 + B - 1) / B), dim3(B), 0, stream, h2, gw2, XW, N);
  hipLaunchKernelGGL((k_gpost<32, 128, 128>), dim3(N / 4), dim3(B), 0, stream,
                     XW, offsets, colA, coefA, selfc, gb2, lg2, lb2,
                     h2, row0, rob0, row1, rob1, out, N);
}